// Round 2
// baseline (285.523 us; speedup 1.0000x reference)
//
#include <hip/hip_runtime.h>

#define BATCH 100000

typedef float v2 __attribute__((ext_vector_type(2)));

__device__ __forceinline__ v2 fma2(v2 a, v2 b, v2 c) { return __builtin_elementwise_fma(a, b, c); }
__device__ __forceinline__ v2 relu2(v2 a) { v2 z = {0.f, 0.f}; return __builtin_elementwise_max(a, z); }
__device__ __forceinline__ v2 splat(float a) { v2 r = {a, a}; return r; }
__device__ __forceinline__ v2 ldv2(const float* p) { return *(const v2*)p; }

// R10 = R9 (hidden-dim split across wave pairs) with the scratch bug fixed.
// R9 post-mortem: `acc[4*t+p]` (runtime t) demoted the whole acc[8] array
// to scratch (rule #20) -> 177 MB WRITE + 172 MB FETCH of scratch traffic,
// VALUBusy 14%, 200 us. Fix: static unroll + per-component cndmask select
// when storing the lane's half to LDS. No other runtime register-array
// indices exist (nb/ob/hsv/tt/acc all static elsewhere).
//
// Structure (validated by R9's occupancy 23->35 even while spilling):
// Block 256 = 2 wave-pairs; wave h of a pair owns hidden units
// [32h,32h+32) of EVERY MLP; sample split across 2 lanes as in R8.
// Doubles waves vs R8 (6252 -> 6.1/SIMD) and halves the per-wave SMEM
// weight stream; weights stay wave-uniform (s_load only).
// Partials combine via LDS (acc 16 f32, rr/ee 2 f32) + 3 syncthreads.
// launch_bounds (256,4): R8/R9 report VGPR=64 -> residency not VGPR-capped.
// Spill tripwire: WRITE_SIZE jump (R3/R6/R9).
__global__ __launch_bounds__(256, 4) void barrier_net(
    const float* __restrict__ x,
    const float* __restrict__ phi_w1, const float* __restrict__ phi_b1,
    const float* __restrict__ phi_w2, const float* __restrict__ phi_b2,
    const float* __restrict__ obs_w1, const float* __restrict__ obs_b1,
    const float* __restrict__ obs_w2, const float* __restrict__ obs_b2,
    const float* __restrict__ rho_w1, const float* __restrict__ rho_b1,
    const float* __restrict__ rho_w2, const float* __restrict__ rho_b2,
    const float* __restrict__ psi_w1, const float* __restrict__ psi_b1,
    const float* __restrict__ psi_w2, const float* __restrict__ psi_b2,
    float2* __restrict__ out)
{
    __shared__ float accL[2][2][32][16];
    __shared__ float rrL[2][2][32][2];
    __shared__ float eeL[2][2][32][2];

    const int lane = threadIdx.x & 63;
    const int wave = threadIdx.x >> 6;
    const int pair = wave >> 1;
    const int h    = wave & 1;       // hidden half owned by this wave
    const int kk   = lane >> 1;      // sample index within the pair-group
    const int t    = lane & 1;       // lane half within the sample
    int s = blockIdx.x * 64 + pair * 32 + kk;
    const bool valid = (s < BATCH);
    if (!valid) s = BATCH - 1;       // clamp: keep loads in-bounds, stay for syncs
    const float* xr = x + (size_t)s * 85;
    const int HB = h * 32;

    // ---- per-lane slice: 8 neighbors ----
    float nb[8][4];
    const int nbase = 5 + 32 * t;
#pragma unroll
    for (int n = 0; n < 8; ++n)
#pragma unroll
        for (int k = 0; k < 4; ++k)
            nb[n][k] = xr[nbase + 4 * n + k];

    // ---- barrier partial: wave 0 only (it does the final store) ----
    float bar0 = 0.f, bar1 = 0.f;
    if (h == 0) {
#pragma unroll
        for (int n = 0; n < 8; ++n) {
            float p0 = -nb[n][0], p1 = -nb[n][1];
            float r  = __builtin_amdgcn_sqrtf(fmaf(p0, p0, p1 * p1));
            float sc = 0.01f * __builtin_amdgcn_rcpf(r - 0.2f);
            bar0 = fmaf(sc, p0, bar0);
            bar1 = fmaf(sc, p1, bar1);
        }
        bar0 += __shfl_xor(bar0, 1);
        bar1 += __shfl_xor(bar1, 1);
    }

    // ---- acc partial: each of the 4 units carries 1/4 of the bias totals
    //      (whole sample needs 16*phi_b2 + 8*obs_b2) ----
    v2 acc[8];
#pragma unroll
    for (int p = 0; p < 8; ++p)
        acc[p] = fma2(splat(4.f), ldv2(phi_b2 + 2 * p),
                 fma2(splat(2.f), ldv2(obs_b2 + 2 * p), splat(0.f)));

    // ---- phi: this wave's 4 hidden chunks (hb in [HB, HB+32)) ----
#pragma unroll 2
    for (int c = 0; c < 4; ++c) {
        const int hb = HB + 8 * c;
        v2 hsv[4] = {{0.f,0.f},{0.f,0.f},{0.f,0.f},{0.f,0.f}};
#pragma unroll
        for (int n = 0; n < 8; ++n) {
#pragma unroll
            for (int p = 0; p < 4; ++p) {
                v2 tv = fma2(splat(nb[n][0]), ldv2(phi_w1 + hb + 2 * p),
                        fma2(splat(nb[n][1]), ldv2(phi_w1 + 64 + hb + 2 * p),
                        fma2(splat(nb[n][2]), ldv2(phi_w1 + 128 + hb + 2 * p),
                        fma2(splat(nb[n][3]), ldv2(phi_w1 + 192 + hb + 2 * p),
                                              ldv2(phi_b1 + hb + 2 * p)))));
                hsv[p] += relu2(tv);
            }
        }
#pragma unroll
        for (int p = 0; p < 4; ++p) {
            const float* r0 = phi_w2 + (size_t)(hb + 2 * p) * 16;
            v2 hx = splat(hsv[p].x), hy = splat(hsv[p].y);
#pragma unroll
            for (int q = 0; q < 8; ++q)
                acc[q] = fma2(hy, ldv2(r0 + 16 + 2 * q),
                         fma2(hx, ldv2(r0 + 2 * q), acc[q]));
        }
    }

    // ---- per-lane slice: 4 observations ----
    float ob[4][2];
    const int obase = 69 + 8 * t;
#pragma unroll
    for (int o = 0; o < 4; ++o) {
        ob[o][0] = xr[obase + 2 * o];
        ob[o][1] = xr[obase + 2 * o + 1];
    }

    // ---- obs: same hidden chunking ----
#pragma unroll 2
    for (int c = 0; c < 4; ++c) {
        const int hb = HB + 8 * c;
        v2 hsv[4] = {{0.f,0.f},{0.f,0.f},{0.f,0.f},{0.f,0.f}};
#pragma unroll
        for (int o = 0; o < 4; ++o) {
#pragma unroll
            for (int p = 0; p < 4; ++p) {
                v2 tv = fma2(splat(ob[o][0]), ldv2(obs_w1 + hb + 2 * p),
                        fma2(splat(ob[o][1]), ldv2(obs_w1 + 64 + hb + 2 * p),
                                              ldv2(obs_b1 + hb + 2 * p)));
                hsv[p] += relu2(tv);
            }
        }
#pragma unroll
        for (int p = 0; p < 4; ++p) {
            const float* r0 = obs_w2 + (size_t)(hb + 2 * p) * 16;
            v2 hx = splat(hsv[p].x), hy = splat(hsv[p].y);
#pragma unroll
            for (int q = 0; q < 8; ++q)
                acc[q] = fma2(hy, ldv2(r0 + 16 + 2 * q),
                         fma2(hx, ldv2(r0 + 2 * q), acc[q]));
        }
    }

    // ---- combine across the lane pair (t) ----
#pragma unroll
    for (int p = 0; p < 8; ++p) {
        acc[p].x += __shfl_xor(acc[p].x, 1);
        acc[p].y += __shfl_xor(acc[p].y, 1);
    }

    // ---- combine across the wave pair (h) via LDS ----
    // NOTE: static indices into acc[] only (R9's acc[4*t+p] demoted the
    // array to scratch). Value-select via cndmask keeps acc in VGPRs.
    {
        float* slot = &accL[pair][h][kk][8 * t];   // runtime LDS addr: fine
#pragma unroll
        for (int p = 0; p < 4; ++p) {
            v2 lo = acc[p], hi = acc[p + 4];
            v2 sel;
            sel.x = t ? hi.x : lo.x;
            sel.y = t ? hi.y : lo.y;
            *(v2*)(slot + 2 * p) = sel;
        }
    }
    __syncthreads();
    {
        const float* oslot = &accL[pair][h ^ 1][kk][0];
#pragma unroll
        for (int p = 0; p < 8; ++p)
            acc[p] += ldv2(oslot + 2 * p);
    }

    const float g0 = xr[0], g1 = xr[1];

    // ---- rho: 16 -> hidden slice [HB,HB+32) -> 2 (partial) ----
    v2 rr = (h == 0) ? ldv2(rho_b2) : splat(0.f);
#pragma unroll 2
    for (int c = 0; c < 4; ++c) {
        const int hb = HB + 8 * c;
        v2 tt[4];
#pragma unroll
        for (int p = 0; p < 4; ++p)
            tt[p] = ldv2(rho_b1 + hb + 2 * p);
#pragma unroll
        for (int j = 0; j < 8; ++j) {
            v2 ax = splat(acc[j].x), ay = splat(acc[j].y);
            const float* rj0 = rho_w1 + (size_t)(2 * j) * 64 + hb;
            const float* rj1 = rho_w1 + (size_t)(2 * j + 1) * 64 + hb;
#pragma unroll
            for (int p = 0; p < 4; ++p)
                tt[p] = fma2(ay, ldv2(rj1 + 2 * p),
                        fma2(ax, ldv2(rj0 + 2 * p), tt[p]));
        }
#pragma unroll
        for (int p = 0; p < 4; ++p) {
            v2 u = relu2(tt[p]);
            rr = fma2(splat(u.x), ldv2(rho_w2 + 2 * (hb + 2 * p)), rr);
            rr = fma2(splat(u.y), ldv2(rho_w2 + 2 * (hb + 2 * p) + 2), rr);
        }
    }
    rrL[pair][h][kk][t] = t ? rr.y : rr.x;   // both lanes hold identical rr
    __syncthreads();
    {
        v2 rro = ldv2(&rrL[pair][h ^ 1][kk][0]);
        rr += rro;                            // full rho output on all 4 units
    }

    // ---- psi: [r0, r1, g0, g1] -> hidden slice -> 2 (partial) ----
    v2 ee = (h == 0) ? ldv2(psi_b2) : splat(0.f);
#pragma unroll 2
    for (int c = 0; c < 4; ++c) {
        const int hb = HB + 8 * c;
#pragma unroll
        for (int p = 0; p < 4; ++p) {
            v2 tv = fma2(splat(rr.x), ldv2(psi_w1 + hb + 2 * p),
                    fma2(splat(rr.y), ldv2(psi_w1 + 64 + hb + 2 * p),
                    fma2(splat(g0),   ldv2(psi_w1 + 128 + hb + 2 * p),
                    fma2(splat(g1),   ldv2(psi_w1 + 192 + hb + 2 * p),
                                      ldv2(psi_b1 + hb + 2 * p)))));
            v2 u = relu2(tv);
            ee = fma2(splat(u.x), ldv2(psi_w2 + 2 * (hb + 2 * p)), ee);
            ee = fma2(splat(u.y), ldv2(psi_w2 + 2 * (hb + 2 * p) + 2), ee);
        }
    }
    eeL[pair][h][kk][t] = t ? ee.y : ee.x;
    __syncthreads();

    if (h == 0 && t == 0 && valid) {
        v2 eeo = ldv2(&eeL[pair][1][kk][0]);
        float a0 = tanhf(tanhf(ee.x + eeo.x) + bar0);
        float a1 = tanhf(tanhf(ee.y + eeo.y) + bar1);
        out[s] = make_float2(2.f * a0, 2.f * a1);
    }
}

extern "C" void kernel_launch(void* const* d_in, const int* in_sizes, int n_in,
                              void* d_out, int out_size, void* d_ws, size_t ws_size,
                              hipStream_t stream) {
    dim3 grid((BATCH + 63) / 64), block(256);   // 64 samples per block
    barrier_net<<<grid, block, 0, stream>>>(
        (const float*)d_in[0],
        (const float*)d_in[1],  (const float*)d_in[2],  (const float*)d_in[3],  (const float*)d_in[4],
        (const float*)d_in[5],  (const float*)d_in[6],  (const float*)d_in[7],  (const float*)d_in[8],
        (const float*)d_in[9],  (const float*)d_in[10], (const float*)d_in[11], (const float*)d_in[12],
        (const float*)d_in[13], (const float*)d_in[14], (const float*)d_in[15], (const float*)d_in[16],
        (float2*)d_out);
}

// Round 3
// 139.829 us; speedup vs baseline: 2.0420x; 2.0420x over previous
//
#include <hip/hip_runtime.h>

#define BATCH 100000

typedef float v2 __attribute__((ext_vector_type(2)));

__device__ __forceinline__ v2 fma2(v2 a, v2 b, v2 c) { return __builtin_elementwise_fma(a, b, c); }
__device__ __forceinline__ v2 relu2(v2 a) { v2 z = {0.f, 0.f}; return __builtin_elementwise_max(a, z); }
__device__ __forceinline__ v2 splat(float a) { v2 r = {a, a}; return r; }
__device__ __forceinline__ v2 ldv2(const float* p) { return *(const v2*)p; }

// R11 = R9/R10 structure with PROVABLE weight-address uniformity.
// R9/R10 post-mortem: counters byte-identical across the two rounds
// (WRITE 177 MB, CONFLICT 200064) -> the acc[4*t+p] fix was irrelevant;
// the real regression is HB = (wave&1)*32 derived from threadIdx.x:
// uniformity analysis calls it divergent, every weight ldv2 became
// per-lane VMEM (SGPR 112 -> 80 = s_load scheme gone), register
// pressure dumped private arrays to scratch (177 MB WRITE tripwire).
// Fix: readfirstlane(h) -> HB is an SGPR fact; fold it into per-MLP
// base pointers ONCE; all loop offsets are again (uniform base +
// uniform loop counter), R8's exact s_load-burst form.
//
// Structure: block 256 = 2 wave-pairs; wave h owns hidden [32h,32h+32)
// of every MLP; sample split across 2 lanes (t). 2x waves vs R8,
// half the per-wave SMEM stream, rho/psi W1 not duplicated.
// Partials combine via LDS (acc 16 f32, rr/ee 2 f32) + 3 syncthreads.
// Spill tripwire: WRITE_SIZE jump (R3/R6/R9/R10).
__global__ __launch_bounds__(256, 4) void barrier_net(
    const float* __restrict__ x,
    const float* __restrict__ phi_w1, const float* __restrict__ phi_b1,
    const float* __restrict__ phi_w2, const float* __restrict__ phi_b2,
    const float* __restrict__ obs_w1, const float* __restrict__ obs_b1,
    const float* __restrict__ obs_w2, const float* __restrict__ obs_b2,
    const float* __restrict__ rho_w1, const float* __restrict__ rho_b1,
    const float* __restrict__ rho_w2, const float* __restrict__ rho_b2,
    const float* __restrict__ psi_w1, const float* __restrict__ psi_b1,
    const float* __restrict__ psi_w2, const float* __restrict__ psi_b2,
    float2* __restrict__ out)
{
    __shared__ float accL[2][2][32][16];
    __shared__ float rrL[2][2][32][2];
    __shared__ float eeL[2][2][32][2];

    const int lane = threadIdx.x & 63;
    const int wave = threadIdx.x >> 6;
    const int pair = wave >> 1;
    const int h    = wave & 1;       // hidden half owned by this wave
    const int kk   = lane >> 1;      // sample index within the pair-group
    const int t    = lane & 1;       // lane half within the sample
    int s = blockIdx.x * 64 + pair * 32 + kk;
    const bool valid = (s < BATCH);
    if (!valid) s = BATCH - 1;       // clamp: keep loads in-bounds, stay for syncs
    const float* xr = x + (size_t)s * 85;

    // ---- uniform hidden-slice base pointers (readfirstlane: the ONLY
    //      place h feeds weight addressing; everything below is
    //      uniform-base + uniform-loop-offset like R8) ----
    const int HB = __builtin_amdgcn_readfirstlane(h) * 32;
    const float* pw1 = phi_w1 + HB;                 // W1 col slice, row stride 64
    const float* pb1 = phi_b1 + HB;
    const float* pw2 = phi_w2 + (size_t)HB * 16;    // W2 row slice
    const float* qw1 = obs_w1 + HB;
    const float* qb1 = obs_b1 + HB;
    const float* qw2 = obs_w2 + (size_t)HB * 16;
    const float* rw1 = rho_w1 + HB;                 // row stride 64
    const float* rb1 = rho_b1 + HB;
    const float* rw2 = rho_w2 + (size_t)HB * 2;
    const float* sw1 = psi_w1 + HB;
    const float* sb1 = psi_b1 + HB;
    const float* sw2 = psi_w2 + (size_t)HB * 2;

    // ---- per-lane slice: 8 neighbors ----
    float nb[8][4];
    const int nbase = 5 + 32 * t;
#pragma unroll
    for (int n = 0; n < 8; ++n)
#pragma unroll
        for (int k = 0; k < 4; ++k)
            nb[n][k] = xr[nbase + 4 * n + k];

    // ---- barrier partial: wave 0 only (it does the final store) ----
    float bar0 = 0.f, bar1 = 0.f;
    if (h == 0) {
#pragma unroll
        for (int n = 0; n < 8; ++n) {
            float p0 = -nb[n][0], p1 = -nb[n][1];
            float r  = __builtin_amdgcn_sqrtf(fmaf(p0, p0, p1 * p1));
            float sc = 0.01f * __builtin_amdgcn_rcpf(r - 0.2f);
            bar0 = fmaf(sc, p0, bar0);
            bar1 = fmaf(sc, p1, bar1);
        }
        bar0 += __shfl_xor(bar0, 1);
        bar1 += __shfl_xor(bar1, 1);
    }

    // ---- acc partial: each of the 4 units carries 1/4 of the bias totals
    //      (whole sample needs 16*phi_b2 + 8*obs_b2) ----
    v2 acc[8];
#pragma unroll
    for (int p = 0; p < 8; ++p)
        acc[p] = fma2(splat(4.f), ldv2(phi_b2 + 2 * p),
                 fma2(splat(2.f), ldv2(obs_b2 + 2 * p), splat(0.f)));

    // ---- phi: this wave's 4 hidden chunks (hb in [0,32) vs slice base) ----
#pragma unroll 2
    for (int c = 0; c < 4; ++c) {
        const int hb = 8 * c;
        v2 hsv[4] = {{0.f,0.f},{0.f,0.f},{0.f,0.f},{0.f,0.f}};
#pragma unroll
        for (int n = 0; n < 8; ++n) {
#pragma unroll
            for (int p = 0; p < 4; ++p) {
                v2 tv = fma2(splat(nb[n][0]), ldv2(pw1 + hb + 2 * p),
                        fma2(splat(nb[n][1]), ldv2(pw1 + 64 + hb + 2 * p),
                        fma2(splat(nb[n][2]), ldv2(pw1 + 128 + hb + 2 * p),
                        fma2(splat(nb[n][3]), ldv2(pw1 + 192 + hb + 2 * p),
                                              ldv2(pb1 + hb + 2 * p)))));
                hsv[p] += relu2(tv);
            }
        }
#pragma unroll
        for (int p = 0; p < 4; ++p) {
            const float* r0 = pw2 + (size_t)(hb + 2 * p) * 16;
            v2 hx = splat(hsv[p].x), hy = splat(hsv[p].y);
#pragma unroll
            for (int q = 0; q < 8; ++q)
                acc[q] = fma2(hy, ldv2(r0 + 16 + 2 * q),
                         fma2(hx, ldv2(r0 + 2 * q), acc[q]));
        }
    }

    // ---- per-lane slice: 4 observations ----
    float ob[4][2];
    const int obase = 69 + 8 * t;
#pragma unroll
    for (int o = 0; o < 4; ++o) {
        ob[o][0] = xr[obase + 2 * o];
        ob[o][1] = xr[obase + 2 * o + 1];
    }

    // ---- obs: same chunking ----
#pragma unroll 2
    for (int c = 0; c < 4; ++c) {
        const int hb = 8 * c;
        v2 hsv[4] = {{0.f,0.f},{0.f,0.f},{0.f,0.f},{0.f,0.f}};
#pragma unroll
        for (int o = 0; o < 4; ++o) {
#pragma unroll
            for (int p = 0; p < 4; ++p) {
                v2 tv = fma2(splat(ob[o][0]), ldv2(qw1 + hb + 2 * p),
                        fma2(splat(ob[o][1]), ldv2(qw1 + 64 + hb + 2 * p),
                                              ldv2(qb1 + hb + 2 * p)));
                hsv[p] += relu2(tv);
            }
        }
#pragma unroll
        for (int p = 0; p < 4; ++p) {
            const float* r0 = qw2 + (size_t)(hb + 2 * p) * 16;
            v2 hx = splat(hsv[p].x), hy = splat(hsv[p].y);
#pragma unroll
            for (int q = 0; q < 8; ++q)
                acc[q] = fma2(hy, ldv2(r0 + 16 + 2 * q),
                         fma2(hx, ldv2(r0 + 2 * q), acc[q]));
        }
    }

    // ---- combine across the lane pair (t) ----
#pragma unroll
    for (int p = 0; p < 8; ++p) {
        acc[p].x += __shfl_xor(acc[p].x, 1);
        acc[p].y += __shfl_xor(acc[p].y, 1);
    }

    // ---- combine across the wave pair (h) via LDS ----
    // Static acc[] indices only; value-select per component.
    {
        float* slot = &accL[pair][h][kk][8 * t];
#pragma unroll
        for (int p = 0; p < 4; ++p) {
            v2 lo = acc[p], hi = acc[p + 4];
            v2 sel;
            sel.x = t ? hi.x : lo.x;
            sel.y = t ? hi.y : lo.y;
            *(v2*)(slot + 2 * p) = sel;
        }
    }
    __syncthreads();
    {
        const float* oslot = &accL[pair][h ^ 1][kk][0];
#pragma unroll
        for (int p = 0; p < 8; ++p)
            acc[p] += ldv2(oslot + 2 * p);
    }

    const float g0 = xr[0], g1 = xr[1];

    // ---- rho: 16 -> hidden slice -> 2 (partial) ----
    v2 rr = (h == 0) ? ldv2(rho_b2) : splat(0.f);
#pragma unroll 2
    for (int c = 0; c < 4; ++c) {
        const int hb = 8 * c;
        v2 tt[4];
#pragma unroll
        for (int p = 0; p < 4; ++p)
            tt[p] = ldv2(rb1 + hb + 2 * p);
#pragma unroll
        for (int j = 0; j < 8; ++j) {
            v2 ax = splat(acc[j].x), ay = splat(acc[j].y);
            const float* rj0 = rw1 + (size_t)(2 * j) * 64 + hb;
            const float* rj1 = rw1 + (size_t)(2 * j + 1) * 64 + hb;
#pragma unroll
            for (int p = 0; p < 4; ++p)
                tt[p] = fma2(ay, ldv2(rj1 + 2 * p),
                        fma2(ax, ldv2(rj0 + 2 * p), tt[p]));
        }
#pragma unroll
        for (int p = 0; p < 4; ++p) {
            v2 u = relu2(tt[p]);
            rr = fma2(splat(u.x), ldv2(rw2 + 2 * (hb + 2 * p)), rr);
            rr = fma2(splat(u.y), ldv2(rw2 + 2 * (hb + 2 * p) + 2), rr);
        }
    }
    rrL[pair][h][kk][t] = t ? rr.y : rr.x;   // both lanes hold identical rr
    __syncthreads();
    {
        v2 rro = ldv2(&rrL[pair][h ^ 1][kk][0]);
        rr += rro;                            // full rho output everywhere
    }

    // ---- psi: [r0, r1, g0, g1] -> hidden slice -> 2 (partial) ----
    v2 ee = (h == 0) ? ldv2(psi_b2) : splat(0.f);
#pragma unroll 2
    for (int c = 0; c < 4; ++c) {
        const int hb = 8 * c;
#pragma unroll
        for (int p = 0; p < 4; ++p) {
            v2 tv = fma2(splat(rr.x), ldv2(sw1 + hb + 2 * p),
                    fma2(splat(rr.y), ldv2(sw1 + 64 + hb + 2 * p),
                    fma2(splat(g0),   ldv2(sw1 + 128 + hb + 2 * p),
                    fma2(splat(g1),   ldv2(sw1 + 192 + hb + 2 * p),
                                      ldv2(sb1 + hb + 2 * p)))));
            v2 u = relu2(tv);
            ee = fma2(splat(u.x), ldv2(sw2 + 2 * (hb + 2 * p)), ee);
            ee = fma2(splat(u.y), ldv2(sw2 + 2 * (hb + 2 * p) + 2), ee);
        }
    }
    eeL[pair][h][kk][t] = t ? ee.y : ee.x;
    __syncthreads();

    if (h == 0 && t == 0 && valid) {
        v2 eeo = ldv2(&eeL[pair][1][kk][0]);
        float a0 = tanhf(tanhf(ee.x + eeo.x) + bar0);
        float a1 = tanhf(tanhf(ee.y + eeo.y) + bar1);
        out[s] = make_float2(2.f * a0, 2.f * a1);
    }
}

extern "C" void kernel_launch(void* const* d_in, const int* in_sizes, int n_in,
                              void* d_out, int out_size, void* d_ws, size_t ws_size,
                              hipStream_t stream) {
    dim3 grid((BATCH + 63) / 64), block(256);   // 64 samples per block
    barrier_net<<<grid, block, 0, stream>>>(
        (const float*)d_in[0],
        (const float*)d_in[1],  (const float*)d_in[2],  (const float*)d_in[3],  (const float*)d_in[4],
        (const float*)d_in[5],  (const float*)d_in[6],  (const float*)d_in[7],  (const float*)d_in[8],
        (const float*)d_in[9],  (const float*)d_in[10], (const float*)d_in[11], (const float*)d_in[12],
        (const float*)d_in[13], (const float*)d_in[14], (const float*)d_in[15], (const float*)d_in[16],
        (float2*)d_out);
}